// Round 1
// 488.278 us; speedup vs baseline: 1.0813x; 1.0813x over previous
//
#include <hip/hip_runtime.h>
#include <math.h>
#include <float.h>

#define BB 8
#define FF 1024
#define NJ 17
#define CH 512
#define TOK 81
#define RCP_SQRT_C 0.04419417382415922f   // 1/sqrt(512)
#define LP 133                            // LDS row pad (stride%32=5, conflict-free col reads)

typedef short bf16x8 __attribute__((ext_vector_type(8)));   // 8 bf16 = 4 VGPRs
typedef float f32x16 __attribute__((ext_vector_type(16)));  // 32x32 MFMA acc

static __device__ inline unsigned short f2bf(float f) {
    __bf16 h = (__bf16)f;                       // RNE
    return __builtin_bit_cast(unsigned short, h);
}
static __device__ inline float bf2f(unsigned short u) {
    return (float)__builtin_bit_cast(__bf16, u);
}

// frag layout: [b][s(32)][h(2)][f(1024)][j(8)] bf16, uint4 index ((b*32+s)*2+h)*1024 + f

// ---------------- kernel 1: mean over joints + sumsq + hi/lo frag write -------
__global__ __launch_bounds__(256) void pool_kernel(const float* __restrict__ x,
                                                   uint4* __restrict__ fhi,
                                                   uint4* __restrict__ flo,
                                                   float* __restrict__ sq,
                                                   unsigned* __restrict__ dmx) {
    const int t = threadIdx.x;
    if (blockIdx.x == 0 && t < BB) dmx[t] = 0u;   // init distmax accumulators (>=0 floats)
    const int wid = t >> 6, lane = t & 63;
    const int row0 = blockIdx.x * 4;            // 4 rows per block, one wave per row
    const int row = row0 + wid;
    const int b = row >> 10, f0 = row0 & 1023;
    const float* px = x + (size_t)row * NJ * CH + lane * 8;
    float a[8] = {};
    #pragma unroll
    for (int n = 0; n < NJ; ++n) {
        const float4 v0 = *(const float4*)(px + (size_t)n * CH);
        const float4 v1 = *(const float4*)(px + (size_t)n * CH + 4);
        a[0] += v0.x; a[1] += v0.y; a[2] += v0.z; a[3] += v0.w;
        a[4] += v1.x; a[5] += v1.y; a[6] += v1.z; a[7] += v1.w;
    }
    float ssq = 0.f;
    unsigned short hi[8], lo[8];
    #pragma unroll
    for (int j = 0; j < 8; ++j) {
        const float m = a[j] / 17.0f;
        ssq += m * m;
        hi[j] = f2bf(m);
        lo[j] = f2bf(m - bf2f(hi[j]));
    }
    #pragma unroll
    for (int off = 32; off > 0; off >>= 1) ssq += __shfl_down(ssq, off);
    if (lane == 0) sq[row] = ssq;

    uint4 uh, ul;
    uh.x = (unsigned)hi[0] | ((unsigned)hi[1] << 16);
    uh.y = (unsigned)hi[2] | ((unsigned)hi[3] << 16);
    uh.z = (unsigned)hi[4] | ((unsigned)hi[5] << 16);
    uh.w = (unsigned)hi[6] | ((unsigned)hi[7] << 16);
    ul.x = (unsigned)lo[0] | ((unsigned)lo[1] << 16);
    ul.y = (unsigned)lo[2] | ((unsigned)lo[3] << 16);
    ul.z = (unsigned)lo[4] | ((unsigned)lo[5] << 16);
    ul.w = (unsigned)lo[6] | ((unsigned)lo[7] << 16);
    __shared__ uint4 sh_hi[256], sh_lo[256];
    sh_hi[lane * 4 + wid] = uh;
    sh_lo[lane * 4 + wid] = ul;
    __syncthreads();
    const int k8 = t >> 2, fpr = t & 3;         // k8 chunk, frame-in-block
    const int s = k8 >> 1, h = k8 & 1;
    const size_t o = (((size_t)b * 32 + s) * 2 + h) * 1024 + f0 + fpr;
    fhi[o] = sh_hi[t];
    flo[o] = sh_lo[t];
}

// ------- kernel 2: split-bf16 MFMA Gram, upper-tri tiles, mirrored store -------
__global__ __launch_bounds__(256) void dist_kernel(const uint4* __restrict__ fhi,
                                                   const uint4* __restrict__ flo,
                                                   const float* __restrict__ sq,
                                                   float* __restrict__ dist) {
    // map blockIdx.x (0..35) -> upper-triangular tile (rt <= ct)
    int tri = blockIdx.x, rt = 0;
    while (tri >= 8 - rt) { tri -= 8 - rt; ++rt; }
    const int ct = rt + tri;
    const bool diag = (rt == ct);
    const int b = blockIdx.z;
    const int tid = threadIdx.x;
    const int w = tid >> 6, lane = tid & 63;
    const int R = rt * 128 + (w & 1) * 64;      // wave rows (2 tiles of 32)
    const int C = ct * 128 + (w >> 1) * 64;     // wave cols
    const int h = lane >> 5, fr = lane & 31;

    size_t a0 = ((size_t)b * 64 + h) * 1024 + R + fr;   // uint4 units; +2048 per k16-step
    size_t b0 = ((size_t)b * 64 + h) * 1024 + C + fr;

    f32x16 acc00, acc01, acc10, acc11;
    #pragma unroll
    for (int i = 0; i < 16; ++i) { acc00[i] = 0.f; acc01[i] = 0.f; acc10[i] = 0.f; acc11[i] = 0.f; }

    bf16x8 A0h = *(const bf16x8*)(fhi + a0), A1h = *(const bf16x8*)(fhi + a0 + 32);
    bf16x8 A0l = *(const bf16x8*)(flo + a0), A1l = *(const bf16x8*)(flo + a0 + 32);
    bf16x8 B0h = *(const bf16x8*)(fhi + b0), B1h = *(const bf16x8*)(fhi + b0 + 32);
    bf16x8 B0l = *(const bf16x8*)(flo + b0), B1l = *(const bf16x8*)(flo + b0 + 32);

    #pragma unroll 4
    for (int s = 0; s < 32; ++s) {
        const bf16x8 cA0h = A0h, cA1h = A1h, cA0l = A0l, cA1l = A1l;
        const bf16x8 cB0h = B0h, cB1h = B1h, cB0l = B0l, cB1l = B1l;
        if (s < 31) {
            a0 += 2048; b0 += 2048;
            A0h = *(const bf16x8*)(fhi + a0); A1h = *(const bf16x8*)(fhi + a0 + 32);
            A0l = *(const bf16x8*)(flo + a0); A1l = *(const bf16x8*)(flo + a0 + 32);
            B0h = *(const bf16x8*)(fhi + b0); B1h = *(const bf16x8*)(fhi + b0 + 32);
            B0l = *(const bf16x8*)(flo + b0); B1l = *(const bf16x8*)(flo + b0 + 32);
        }
        acc00 = __builtin_amdgcn_mfma_f32_32x32x16_bf16(cA0h, cB0h, acc00, 0, 0, 0);
        acc01 = __builtin_amdgcn_mfma_f32_32x32x16_bf16(cA0h, cB1h, acc01, 0, 0, 0);
        acc10 = __builtin_amdgcn_mfma_f32_32x32x16_bf16(cA1h, cB0h, acc10, 0, 0, 0);
        acc11 = __builtin_amdgcn_mfma_f32_32x32x16_bf16(cA1h, cB1h, acc11, 0, 0, 0);
        acc00 = __builtin_amdgcn_mfma_f32_32x32x16_bf16(cA0h, cB0l, acc00, 0, 0, 0);
        acc01 = __builtin_amdgcn_mfma_f32_32x32x16_bf16(cA0h, cB1l, acc01, 0, 0, 0);
        acc10 = __builtin_amdgcn_mfma_f32_32x32x16_bf16(cA1h, cB0l, acc10, 0, 0, 0);
        acc11 = __builtin_amdgcn_mfma_f32_32x32x16_bf16(cA1h, cB1l, acc11, 0, 0, 0);
        acc00 = __builtin_amdgcn_mfma_f32_32x32x16_bf16(cA0l, cB0h, acc00, 0, 0, 0);
        acc01 = __builtin_amdgcn_mfma_f32_32x32x16_bf16(cA0l, cB1h, acc01, 0, 0, 0);
        acc10 = __builtin_amdgcn_mfma_f32_32x32x16_bf16(cA1l, cB0h, acc10, 0, 0, 0);
        acc11 = __builtin_amdgcn_mfma_f32_32x32x16_bf16(cA1l, cB1h, acc11, 0, 0, 0);
    }

    // ---- epilogue: two phases through a 64x128 LDS stage; mirrored stores ----
    __shared__ float lds[64 * LP];
    const int bF = b * FF;
    const int R0 = rt * 128, C0 = ct * 128;
    const float sqc0 = sq[bF + C + fr], sqc1 = sq[bF + C + fr + 32];
    const int lcb = (w >> 1) * 64 + fr;         // local col base in 0..127

    #pragma unroll
    for (int p = 0; p < 2; ++p) {
        if ((w & 1) == p) {                     // this wave's rows belong to phase p
            #pragma unroll
            for (int reg = 0; reg < 16; ++reg) {
                const int rp = 4 * h + (reg & 3) + 8 * (reg >> 2);   // 0..31
                const float sqr0 = sq[bF + R + rp];
                const float sqr1 = sq[bF + R + rp + 32];
                lds[rp * LP + lcb] =
                    sqrtf(fmaxf(sqr0 + sqc0 - 2.0f * acc00[reg], 0.f)) * RCP_SQRT_C;
                lds[rp * LP + lcb + 32] =
                    sqrtf(fmaxf(sqr0 + sqc1 - 2.0f * acc01[reg], 0.f)) * RCP_SQRT_C;
                lds[(rp + 32) * LP + lcb] =
                    sqrtf(fmaxf(sqr1 + sqc0 - 2.0f * acc10[reg], 0.f)) * RCP_SQRT_C;
                lds[(rp + 32) * LP + lcb + 32] =
                    sqrtf(fmaxf(sqr1 + sqc1 - 2.0f * acc11[reg], 0.f)) * RCP_SQRT_C;
            }
        }
        __syncthreads();
        if (!diag) {
            // direct: rows R0+p*64+lr, cols C0..C0+127 (coalesced)
            for (int q = tid; q < 64 * 128; q += 256) {
                const int lr = q >> 7, c = q & 127;
                dist[((size_t)bF + R0 + p * 64 + lr) * FF + C0 + c] = lds[lr * LP + c];
            }
            // mirror: rows C0+c, cols R0+p*64+lr (lanes along lr -> coalesced)
            for (int q = tid; q < 64 * 128; q += 256) {
                const int lr = q & 63, c = q >> 6;
                dist[((size_t)bF + C0 + c) * FF + R0 + p * 64 + lr] = lds[lr * LP + c];
            }
        } else if (p == 0) {
            // rows i=0..63, all cols: canonical upper value (0 on diagonal)
            for (int q = tid; q < 64 * 128; q += 256) {
                const int i = q >> 7, j = q & 127;
                const float v = (i == j) ? 0.f : (i < j ? lds[i * LP + j] : lds[j * LP + i]);
                dist[((size_t)bF + R0 + i) * FF + C0 + j] = v;
            }
            // rows i=64..127, cols j=0..63: mirror of staged (j, i)
            for (int q = tid; q < 64 * 64; q += 256) {
                const int i = 64 + (q >> 6), j = q & 63;
                dist[((size_t)bF + R0 + i) * FF + C0 + j] = lds[j * LP + i];
            }
        } else {
            // rows i=64..127, cols j=64..127: canonical within staged rows 64..127
            for (int q = tid; q < 64 * 64; q += 256) {
                const int i = 64 + (q >> 6), j = 64 + (q & 63);
                const float v = (i == j) ? 0.f
                               : (i < j ? lds[(i - 64) * LP + j] : lds[(j - 64) * LP + i]);
                dist[((size_t)bF + R0 + i) * FF + C0 + j] = v;
            }
        }
        __syncthreads();
    }
}

__device__ inline void merge2(float& lo0, float& lo1, float c0, float c1) {
    float n0 = fminf(lo0, c0);
    float n1 = fminf(fmaxf(lo0, c0), fminf(lo1, c1));
    lo0 = n0; lo1 = n1;
}

// ------- kernel 3: per-row two-smallest + rowmax -> density; fused batch max -------
__global__ __launch_bounds__(256) void rowstat_kernel(const float* __restrict__ dist,
                                                      const float* __restrict__ noise,
                                                      float* __restrict__ density,
                                                      unsigned* __restrict__ dmx) {
    const int wid = threadIdx.x >> 6;
    const int r = blockIdx.x * 4 + wid;
    const int lane = threadIdx.x & 63;
    const float* dr = dist + (size_t)r * FF;
    float lo0 = FLT_MAX, lo1 = FLT_MAX, mx = -FLT_MAX;
    #pragma unroll
    for (int j = 0; j < FF / 64; ++j) {
        const float d = dr[lane + j * 64];
        mx = fmaxf(mx, d);
        merge2(lo0, lo1, d, FLT_MAX);
    }
    #pragma unroll
    for (int off = 32; off > 0; off >>= 1) {
        const float o0 = __shfl_down(lo0, off);
        const float o1 = __shfl_down(lo1, off);
        const float om = __shfl_down(mx, off);
        merge2(lo0, lo1, o0, o1);
        mx = fmaxf(mx, om);
    }
    __shared__ float wmx[4];
    if (lane == 0) {
        density[r] = expf(-0.5f * (lo0 * lo0 + lo1 * lo1)) + noise[r] * 1e-6f;
        wmx[wid] = mx;
    }
    __syncthreads();
    if (threadIdx.x == 0) {
        const float m = fmaxf(fmaxf(wmx[0], wmx[1]), fmaxf(wmx[2], wmx[3]));
        // distances are >= 0, so float bits compare monotonically as unsigned
        atomicMax(&dmx[blockIdx.x >> 8], __float_as_uint(m));
    }
}

// ---------------- kernel 4: per-row masked min -> score ----------------
__global__ __launch_bounds__(256) void scoremin_kernel(const float* __restrict__ dist,
                                                       const float* __restrict__ density,
                                                       const float* __restrict__ distmax,
                                                       float* __restrict__ score) {
    const int r = blockIdx.x * 4 + (threadIdx.x >> 6);
    const int lane = threadIdx.x & 63;
    const int b = r >> 10;
    const float* dr = dist + (size_t)r * FF;
    const float* db = density + (size_t)b * FF;
    const float dme = density[r];
    float mn = FLT_MAX;
    #pragma unroll
    for (int j = 0; j < FF / 64; ++j) {
        const int c = lane + j * 64;
        if (db[c] > dme) mn = fminf(mn, dr[c]);
    }
    #pragma unroll
    for (int off = 32; off > 0; off >>= 1) mn = fminf(mn, __shfl_down(mn, off));
    if (lane == 0) {
        if (mn == FLT_MAX) mn = distmax[b];
        score[r] = mn * dme;
    }
}

// -------- kernel 5: exact top-81 via MSB byte-radix select + ballot compaction --------
// Selection set: all scores > T plus the kk smallest-index scores == T, where T is the
// 81st-largest value. Matches lax.top_k stable (smallest-index-first) tie semantics.
// Output written directly in ascending index order.
__global__ __launch_bounds__(256) void topk_kernel(const float* __restrict__ score,
                                                   int* __restrict__ selsort) {
    const int b = blockIdx.x, t = threadIdx.x;
    const int w = t >> 6, lane = t & 63;
    const float* sb = score + b * FF;
    // scores are >= 0 (dist >= 0, density > 0) -> bits compare monotonically as unsigned
    unsigned v[4];
    #pragma unroll
    for (int j = 0; j < 4; ++j) v[j] = __float_as_uint(sb[t + 256 * j]);   // index i = t + 256*j

    __shared__ unsigned hist[256];
    __shared__ unsigned wtot[4];
    __shared__ unsigned sh_byte, sh_kk;
    unsigned prefix = 0, kk = TOK;
    #pragma unroll
    for (int pass = 0; pass < 4; ++pass) {
        const int sh = 24 - 8 * pass;
        const unsigned pmask = (pass == 0) ? 0u : (0xFFFFFFFFu << (sh + 8));
        hist[t] = 0;
        __syncthreads();
        #pragma unroll
        for (int j = 0; j < 4; ++j)
            if ((v[j] & pmask) == prefix) atomicAdd(&hist[(v[j] >> sh) & 255], 1u);
        __syncthreads();
        const unsigned cnt = hist[t];           // bin t count
        unsigned s = cnt;                       // inclusive suffix over lanes within wave
        #pragma unroll
        for (int off = 1; off < 64; off <<= 1) {
            const unsigned o = __shfl_down(s, off);
            if (lane + off < 64) s += o;
        }
        if (lane == 0) wtot[w] = s;
        __syncthreads();
        unsigned hi2 = 0;
        for (int w2 = w + 1; w2 < 4; ++w2) hi2 += wtot[w2];
        const unsigned S_incl = s + hi2;        // count of values in bins >= t
        const unsigned S_excl = S_incl - cnt;   // count of values in bins >  t
        if (S_excl < kk && kk <= S_incl) { sh_byte = (unsigned)t; sh_kk = kk - S_excl; }
        __syncthreads();
        prefix |= (sh_byte << sh);
        kk = sh_kk;
    }
    const unsigned T = prefix;                  // exact 81st-largest value (bits)

    // --- compaction: emit indices of (v > T) plus first-kk (v == T), index-ascending ---
    __shared__ unsigned cgt[16], ceq[16];       // per-64-chunk counts, chunk c = i>>6 = j*4+w
    unsigned long long bgt[4], beq[4];
    #pragma unroll
    for (int j = 0; j < 4; ++j) {
        bgt[j] = __ballot(v[j] > T);
        beq[j] = __ballot(v[j] == T);
        if (lane == 0) {
            cgt[j * 4 + w] = (unsigned)__popcll(bgt[j]);
            ceq[j * 4 + w] = (unsigned)__popcll(beq[j]);
        }
    }
    __syncthreads();
    const unsigned long long below = (1ULL << lane) - 1ULL;   // lanes < lane
    #pragma unroll
    for (int j = 0; j < 4; ++j) {
        const bool gt = v[j] > T, eq = v[j] == T;
        if (!gt && !eq) continue;
        const int c = j * 4 + w;
        unsigned bq_gt = 0, bq_eq = 0;
        for (int cc = 0; cc < c; ++cc) { bq_gt += cgt[cc]; bq_eq += ceq[cc]; }
        const unsigned wgt = (unsigned)__popcll(bgt[j] & below);
        const unsigned weq = (unsigned)__popcll(beq[j] & below);
        unsigned pos;
        if (gt) {
            const unsigned eq_before = bq_eq + weq;
            pos = bq_gt + wgt + ((eq_before < kk) ? eq_before : kk);
        } else {
            const unsigned e = bq_eq + weq;     // global tie rank (index order)
            if (e >= kk) continue;
            pos = bq_gt + wgt + e;
        }
        selsort[b * TOK + pos] = (int)(t + 256 * j);
    }
}

// ---------------- kernel 6: gather + pos-embed ----------------
__global__ __launch_bounds__(256) void gather_kernel(const float* __restrict__ x,
                                                     const float* __restrict__ pos,
                                                     const int* __restrict__ selsort,
                                                     float* __restrict__ out) {
    const size_t i = (size_t)blockIdx.x * 256 + threadIdx.x;
    const size_t total = (size_t)BB * TOK * NJ * (CH / 4);
    if (i >= total) return;
    const int c4 = (int)(i & (CH / 4 - 1));
    size_t r = i >> 7;
    const int n = (int)(r % NJ); r /= NJ;
    const int t = (int)(r % TOK);
    const int b = (int)(r / TOK);
    const int f = selsort[b * TOK + t];
    float4 v = *(const float4*)(x + (((size_t)(b * FF + f)) * NJ + n) * CH + c4 * 4);
    const float4 p = *(const float4*)(pos + (size_t)t * CH + c4 * 4);
    v.x += p.x; v.y += p.y; v.z += p.z; v.w += p.w;
    *(float4*)(out + i * 4) = v;
}

extern "C" void kernel_launch(void* const* d_in, const int* in_sizes, int n_in,
                              void* d_out, int out_size, void* d_ws, size_t ws_size,
                              hipStream_t stream) {
    const float* x     = (const float*)d_in[0];
    const float* pos   = (const float*)d_in[1];
    const float* noise = (const float*)d_in[2];
    float* out = (float*)d_out;

    uint4* fhi    = (uint4*)d_ws;                           // 8 MB
    uint4* flo    = fhi + (size_t)BB * 32 * 2 * 1024;       // 8 MB
    float* dist   = (float*)(flo + (size_t)BB * 32 * 2 * 1024);  // 33.5 MB
    float* sq     = dist + (size_t)BB * FF * FF;
    float* density = sq + BB * FF;
    float* distmax = density + BB * FF;                     // 8 floats (atomicMax as uint)
    float* score   = distmax + 8;
    int*   selsort = (int*)(score + BB * FF);

    pool_kernel<<<(BB * FF) / 4, 256, 0, stream>>>(x, fhi, flo, sq, (unsigned*)distmax);
    dim3 g(36, 1, BB);                                      // upper-tri 128x128 tiles
    dist_kernel<<<g, 256, 0, stream>>>(fhi, flo, sq, dist);
    rowstat_kernel<<<(BB * FF) / 4, 256, 0, stream>>>(dist, noise, density, (unsigned*)distmax);
    scoremin_kernel<<<(BB * FF) / 4, 256, 0, stream>>>(dist, density, distmax, score);
    topk_kernel<<<BB, 256, 0, stream>>>(score, selsort);
    const int gtot = (int)(((size_t)BB * TOK * NJ * (CH / 4) + 255) / 256);
    gather_kernel<<<gtot, 256, 0, stream>>>(x, pos, selsort, out);
}

// Round 2
// 483.338 us; speedup vs baseline: 1.0923x; 1.0102x over previous
//
#include <hip/hip_runtime.h>
#include <math.h>
#include <float.h>

#define BB 8
#define FF 1024
#define NJ 17
#define CH 512
#define TOK 81
#define RCP_SQRT_C 0.04419417382415922f   // 1/sqrt(512)
#define LP 133                            // LDS row pad (stride%32=5, conflict-free col reads)

typedef short bf16x8 __attribute__((ext_vector_type(8)));   // 8 bf16 = 4 VGPRs
typedef float f32x16 __attribute__((ext_vector_type(16)));  // 32x32 MFMA acc

static __device__ inline unsigned short f2bf(float f) {
    __bf16 h = (__bf16)f;                       // RNE
    return __builtin_bit_cast(unsigned short, h);
}
static __device__ inline float bf2f(unsigned short u) {
    return (float)__builtin_bit_cast(__bf16, u);
}

// frag layout: [b][s(32)][h(2)][f(1024)][j(8)] bf16, uint4 index ((b*32+s)*2+h)*1024 + f

// ---------------- kernel 1: mean over joints + sumsq + hi/lo frag write -------
__global__ __launch_bounds__(256) void pool_kernel(const float* __restrict__ x,
                                                   uint4* __restrict__ fhi,
                                                   uint4* __restrict__ flo,
                                                   float* __restrict__ sq,
                                                   unsigned* __restrict__ dmx) {
    const int t = threadIdx.x;
    if (blockIdx.x == 0 && t < BB) dmx[t] = 0u;   // init distmax accumulators (>=0 floats)
    const int wid = t >> 6, lane = t & 63;
    const int row0 = blockIdx.x * 4;            // 4 rows per block, one wave per row
    const int row = row0 + wid;
    const int b = row >> 10, f0 = row0 & 1023;
    const float* px = x + (size_t)row * NJ * CH + lane * 8;
    float a[8] = {};
    #pragma unroll
    for (int n = 0; n < NJ; ++n) {
        const float4 v0 = *(const float4*)(px + (size_t)n * CH);
        const float4 v1 = *(const float4*)(px + (size_t)n * CH + 4);
        a[0] += v0.x; a[1] += v0.y; a[2] += v0.z; a[3] += v0.w;
        a[4] += v1.x; a[5] += v1.y; a[6] += v1.z; a[7] += v1.w;
    }
    float ssq = 0.f;
    unsigned short hi[8], lo[8];
    #pragma unroll
    for (int j = 0; j < 8; ++j) {
        const float m = a[j] / 17.0f;
        ssq += m * m;
        hi[j] = f2bf(m);
        lo[j] = f2bf(m - bf2f(hi[j]));
    }
    #pragma unroll
    for (int off = 32; off > 0; off >>= 1) ssq += __shfl_down(ssq, off);
    if (lane == 0) sq[row] = ssq;

    uint4 uh, ul;
    uh.x = (unsigned)hi[0] | ((unsigned)hi[1] << 16);
    uh.y = (unsigned)hi[2] | ((unsigned)hi[3] << 16);
    uh.z = (unsigned)hi[4] | ((unsigned)hi[5] << 16);
    uh.w = (unsigned)hi[6] | ((unsigned)hi[7] << 16);
    ul.x = (unsigned)lo[0] | ((unsigned)lo[1] << 16);
    ul.y = (unsigned)lo[2] | ((unsigned)lo[3] << 16);
    ul.z = (unsigned)lo[4] | ((unsigned)lo[5] << 16);
    ul.w = (unsigned)lo[6] | ((unsigned)lo[7] << 16);
    __shared__ uint4 sh_hi[256], sh_lo[256];
    sh_hi[lane * 4 + wid] = uh;
    sh_lo[lane * 4 + wid] = ul;
    __syncthreads();
    const int k8 = t >> 2, fpr = t & 3;         // k8 chunk, frame-in-block
    const int s = k8 >> 1, h = k8 & 1;
    const size_t o = (((size_t)b * 32 + s) * 2 + h) * 1024 + f0 + fpr;
    fhi[o] = sh_hi[t];
    flo[o] = sh_lo[t];
}

// ------- kernel 2: split-bf16 MFMA Gram, upper-tri tiles, mirrored store -------
// Flat grid of 288; batch = id & 7 so the id%8 -> XCD round-robin pins each batch's
// 2 MB operand panel set onto one XCD's L2 (perf-only remap).
__global__ __launch_bounds__(256) void dist_kernel(const uint4* __restrict__ fhi,
                                                   const uint4* __restrict__ flo,
                                                   const float* __restrict__ sq,
                                                   float* __restrict__ dist) {
    const int b = blockIdx.x & 7;
    int tri = blockIdx.x >> 3, rt = 0;          // 0..35 -> upper-tri tile (rt <= ct)
    while (tri >= 8 - rt) { tri -= 8 - rt; ++rt; }
    const int ct = rt + tri;
    const bool diag = (rt == ct);
    const int tid = threadIdx.x;
    const int w = tid >> 6, lane = tid & 63;
    const int R = rt * 128 + (w & 1) * 64;      // wave rows (2 tiles of 32)
    const int C = ct * 128 + (w >> 1) * 64;     // wave cols
    const int h = lane >> 5, fr = lane & 31;

    size_t a0 = ((size_t)b * 64 + h) * 1024 + R + fr;   // uint4 units; +2048 per k16-step
    size_t b0 = ((size_t)b * 64 + h) * 1024 + C + fr;

    f32x16 acc00, acc01, acc10, acc11;
    #pragma unroll
    for (int i = 0; i < 16; ++i) { acc00[i] = 0.f; acc01[i] = 0.f; acc10[i] = 0.f; acc11[i] = 0.f; }

    bf16x8 A0h = *(const bf16x8*)(fhi + a0), A1h = *(const bf16x8*)(fhi + a0 + 32);
    bf16x8 A0l = *(const bf16x8*)(flo + a0), A1l = *(const bf16x8*)(flo + a0 + 32);
    bf16x8 B0h = *(const bf16x8*)(fhi + b0), B1h = *(const bf16x8*)(fhi + b0 + 32);
    bf16x8 B0l = *(const bf16x8*)(flo + b0), B1l = *(const bf16x8*)(flo + b0 + 32);

    #pragma unroll 4
    for (int s = 0; s < 32; ++s) {
        const bf16x8 cA0h = A0h, cA1h = A1h, cA0l = A0l, cA1l = A1l;
        const bf16x8 cB0h = B0h, cB1h = B1h, cB0l = B0l, cB1l = B1l;
        if (s < 31) {
            a0 += 2048; b0 += 2048;
            A0h = *(const bf16x8*)(fhi + a0); A1h = *(const bf16x8*)(fhi + a0 + 32);
            A0l = *(const bf16x8*)(flo + a0); A1l = *(const bf16x8*)(flo + a0 + 32);
            B0h = *(const bf16x8*)(fhi + b0); B1h = *(const bf16x8*)(fhi + b0 + 32);
            B0l = *(const bf16x8*)(flo + b0); B1l = *(const bf16x8*)(flo + b0 + 32);
        }
        acc00 = __builtin_amdgcn_mfma_f32_32x32x16_bf16(cA0h, cB0h, acc00, 0, 0, 0);
        acc01 = __builtin_amdgcn_mfma_f32_32x32x16_bf16(cA0h, cB1h, acc01, 0, 0, 0);
        acc10 = __builtin_amdgcn_mfma_f32_32x32x16_bf16(cA1h, cB0h, acc10, 0, 0, 0);
        acc11 = __builtin_amdgcn_mfma_f32_32x32x16_bf16(cA1h, cB1h, acc11, 0, 0, 0);
        acc00 = __builtin_amdgcn_mfma_f32_32x32x16_bf16(cA0h, cB0l, acc00, 0, 0, 0);
        acc01 = __builtin_amdgcn_mfma_f32_32x32x16_bf16(cA0h, cB1l, acc01, 0, 0, 0);
        acc10 = __builtin_amdgcn_mfma_f32_32x32x16_bf16(cA1h, cB0l, acc10, 0, 0, 0);
        acc11 = __builtin_amdgcn_mfma_f32_32x32x16_bf16(cA1h, cB1l, acc11, 0, 0, 0);
        acc00 = __builtin_amdgcn_mfma_f32_32x32x16_bf16(cA0l, cB0h, acc00, 0, 0, 0);
        acc01 = __builtin_amdgcn_mfma_f32_32x32x16_bf16(cA0l, cB1h, acc01, 0, 0, 0);
        acc10 = __builtin_amdgcn_mfma_f32_32x32x16_bf16(cA1l, cB0h, acc10, 0, 0, 0);
        acc11 = __builtin_amdgcn_mfma_f32_32x32x16_bf16(cA1l, cB1h, acc11, 0, 0, 0);
    }

    // ---- epilogue: two phases through a 64x128 LDS stage; mirrored stores ----
    __shared__ float lds[64 * LP];
    const int bF = b * FF;
    const int R0 = rt * 128, C0 = ct * 128;
    const float sqc0 = sq[bF + C + fr], sqc1 = sq[bF + C + fr + 32];
    const int lcb = (w >> 1) * 64 + fr;         // local col base in 0..127

    #pragma unroll
    for (int p = 0; p < 2; ++p) {
        if ((w & 1) == p) {                     // this wave's rows belong to phase p
            #pragma unroll
            for (int reg = 0; reg < 16; ++reg) {
                const int rp = 4 * h + (reg & 3) + 8 * (reg >> 2);   // 0..31
                const float sqr0 = sq[bF + R + rp];
                const float sqr1 = sq[bF + R + rp + 32];
                lds[rp * LP + lcb] =
                    sqrtf(fmaxf(sqr0 + sqc0 - 2.0f * acc00[reg], 0.f)) * RCP_SQRT_C;
                lds[rp * LP + lcb + 32] =
                    sqrtf(fmaxf(sqr0 + sqc1 - 2.0f * acc01[reg], 0.f)) * RCP_SQRT_C;
                lds[(rp + 32) * LP + lcb] =
                    sqrtf(fmaxf(sqr1 + sqc0 - 2.0f * acc10[reg], 0.f)) * RCP_SQRT_C;
                lds[(rp + 32) * LP + lcb + 32] =
                    sqrtf(fmaxf(sqr1 + sqc1 - 2.0f * acc11[reg], 0.f)) * RCP_SQRT_C;
            }
        }
        __syncthreads();
        if (!diag) {
            // direct: rows R0+p*64+lr, cols C0..C0+127 (coalesced)
            for (int q = tid; q < 64 * 128; q += 256) {
                const int lr = q >> 7, c = q & 127;
                dist[((size_t)bF + R0 + p * 64 + lr) * FF + C0 + c] = lds[lr * LP + c];
            }
            // mirror: rows C0+c, cols R0+p*64+lr (lanes along lr -> coalesced)
            for (int q = tid; q < 64 * 128; q += 256) {
                const int lr = q & 63, c = q >> 6;
                dist[((size_t)bF + C0 + c) * FF + R0 + p * 64 + lr] = lds[lr * LP + c];
            }
        } else if (p == 0) {
            // rows i=0..63, all cols: canonical upper value (0 on diagonal)
            for (int q = tid; q < 64 * 128; q += 256) {
                const int i = q >> 7, j = q & 127;
                const float v = (i == j) ? 0.f : (i < j ? lds[i * LP + j] : lds[j * LP + i]);
                dist[((size_t)bF + R0 + i) * FF + C0 + j] = v;
            }
            // rows i=64..127, cols j=0..63: mirror of staged (j, i)
            for (int q = tid; q < 64 * 64; q += 256) {
                const int i = 64 + (q >> 6), j = q & 63;
                dist[((size_t)bF + R0 + i) * FF + C0 + j] = lds[j * LP + i];
            }
        } else {
            // rows i=64..127, cols j=64..127: canonical within staged rows 64..127
            for (int q = tid; q < 64 * 64; q += 256) {
                const int i = 64 + (q >> 6), j = 64 + (q & 63);
                const float v = (i == j) ? 0.f
                               : (i < j ? lds[(i - 64) * LP + j] : lds[(j - 64) * LP + i]);
                dist[((size_t)bF + R0 + i) * FF + C0 + j] = v;
            }
        }
        __syncthreads();
    }
}

__device__ inline void merge2(float& lo0, float& lo1, float c0, float c1) {
    float n0 = fminf(lo0, c0);
    float n1 = fminf(fmaxf(lo0, c0), fminf(lo1, c1));
    lo0 = n0; lo1 = n1;
}

// ------- kernel 3: per-row two-smallest + rowmax -> density; fused batch max -------
// float4 loads: 16 B/lane, exact (min/max reductions are order-independent)
__global__ __launch_bounds__(256) void rowstat_kernel(const float* __restrict__ dist,
                                                      const float* __restrict__ noise,
                                                      float* __restrict__ density,
                                                      unsigned* __restrict__ dmx) {
    const int wid = threadIdx.x >> 6;
    const int r = blockIdx.x * 4 + wid;
    const int lane = threadIdx.x & 63;
    const float* dr = dist + (size_t)r * FF + lane * 4;
    float lo0 = FLT_MAX, lo1 = FLT_MAX, mx = -FLT_MAX;
    #pragma unroll
    for (int j = 0; j < 4; ++j) {
        const float4 d = *(const float4*)(dr + j * 256);
        mx = fmaxf(mx, fmaxf(fmaxf(d.x, d.y), fmaxf(d.z, d.w)));
        merge2(lo0, lo1, fminf(d.x, d.y), fmaxf(d.x, d.y));
        merge2(lo0, lo1, fminf(d.z, d.w), fmaxf(d.z, d.w));
    }
    #pragma unroll
    for (int off = 32; off > 0; off >>= 1) {
        const float o0 = __shfl_down(lo0, off);
        const float o1 = __shfl_down(lo1, off);
        const float om = __shfl_down(mx, off);
        merge2(lo0, lo1, o0, o1);
        mx = fmaxf(mx, om);
    }
    __shared__ float wmx[4];
    if (lane == 0) {
        density[r] = expf(-0.5f * (lo0 * lo0 + lo1 * lo1)) + noise[r] * 1e-6f;
        wmx[wid] = mx;
    }
    __syncthreads();
    if (threadIdx.x == 0) {
        const float m = fmaxf(fmaxf(wmx[0], wmx[1]), fmaxf(wmx[2], wmx[3]));
        // distances are >= 0, so float bits compare monotonically as unsigned
        atomicMax(&dmx[blockIdx.x >> 8], __float_as_uint(m));
    }
}

// ---------------- kernel 4: per-row masked min -> score ----------------
__global__ __launch_bounds__(256) void scoremin_kernel(const float* __restrict__ dist,
                                                       const float* __restrict__ density,
                                                       const float* __restrict__ distmax,
                                                       float* __restrict__ score) {
    const int r = blockIdx.x * 4 + (threadIdx.x >> 6);
    const int lane = threadIdx.x & 63;
    const int b = r >> 10;
    const float* dr = dist + (size_t)r * FF + lane * 4;
    const float* db = density + (size_t)b * FF + lane * 4;
    const float dme = density[r];
    float mn = FLT_MAX;
    #pragma unroll
    for (int j = 0; j < 4; ++j) {
        const float4 d = *(const float4*)(dr + j * 256);
        const float4 de = *(const float4*)(db + j * 256);
        mn = fminf(mn, (de.x > dme) ? d.x : FLT_MAX);
        mn = fminf(mn, (de.y > dme) ? d.y : FLT_MAX);
        mn = fminf(mn, (de.z > dme) ? d.z : FLT_MAX);
        mn = fminf(mn, (de.w > dme) ? d.w : FLT_MAX);
    }
    #pragma unroll
    for (int off = 32; off > 0; off >>= 1) mn = fminf(mn, __shfl_down(mn, off));
    if (lane == 0) {
        if (mn == FLT_MAX) mn = distmax[b];
        score[r] = mn * dme;
    }
}

// -------- kernel 5: exact top-81 via MSB byte-radix select + ballot compaction --------
// Selection set: all scores > T plus the kk smallest-index scores == T, where T is the
// 81st-largest value. Matches lax.top_k stable (smallest-index-first) tie semantics.
// Output written directly in ascending index order.
__global__ __launch_bounds__(256) void topk_kernel(const float* __restrict__ score,
                                                   int* __restrict__ selsort) {
    const int b = blockIdx.x, t = threadIdx.x;
    const int w = t >> 6, lane = t & 63;
    const float* sb = score + b * FF;
    // scores are >= 0 (dist >= 0, density > 0) -> bits compare monotonically as unsigned
    unsigned v[4];
    #pragma unroll
    for (int j = 0; j < 4; ++j) v[j] = __float_as_uint(sb[t + 256 * j]);   // index i = t + 256*j

    __shared__ unsigned hist[256];
    __shared__ unsigned wtot[4];
    __shared__ unsigned sh_byte, sh_kk;
    unsigned prefix = 0, kk = TOK;
    #pragma unroll
    for (int pass = 0; pass < 4; ++pass) {
        const int sh = 24 - 8 * pass;
        const unsigned pmask = (pass == 0) ? 0u : (0xFFFFFFFFu << (sh + 8));
        hist[t] = 0;
        __syncthreads();
        #pragma unroll
        for (int j = 0; j < 4; ++j)
            if ((v[j] & pmask) == prefix) atomicAdd(&hist[(v[j] >> sh) & 255], 1u);
        __syncthreads();
        const unsigned cnt = hist[t];           // bin t count
        unsigned s = cnt;                       // inclusive suffix over lanes within wave
        #pragma unroll
        for (int off = 1; off < 64; off <<= 1) {
            const unsigned o = __shfl_down(s, off);
            if (lane + off < 64) s += o;
        }
        if (lane == 0) wtot[w] = s;
        __syncthreads();
        unsigned hi2 = 0;
        for (int w2 = w + 1; w2 < 4; ++w2) hi2 += wtot[w2];
        const unsigned S_incl = s + hi2;        // count of values in bins >= t
        const unsigned S_excl = S_incl - cnt;   // count of values in bins >  t
        if (S_excl < kk && kk <= S_incl) { sh_byte = (unsigned)t; sh_kk = kk - S_excl; }
        __syncthreads();
        prefix |= (sh_byte << sh);
        kk = sh_kk;
    }
    const unsigned T = prefix;                  // exact 81st-largest value (bits)

    // --- compaction: emit indices of (v > T) plus first-kk (v == T), index-ascending ---
    __shared__ unsigned cgt[16], ceq[16];       // per-64-chunk counts, chunk c = i>>6 = j*4+w
    unsigned long long bgt[4], beq[4];
    #pragma unroll
    for (int j = 0; j < 4; ++j) {
        bgt[j] = __ballot(v[j] > T);
        beq[j] = __ballot(v[j] == T);
        if (lane == 0) {
            cgt[j * 4 + w] = (unsigned)__popcll(bgt[j]);
            ceq[j * 4 + w] = (unsigned)__popcll(beq[j]);
        }
    }
    __syncthreads();
    const unsigned long long below = (1ULL << lane) - 1ULL;   // lanes < lane
    #pragma unroll
    for (int j = 0; j < 4; ++j) {
        const bool gt = v[j] > T, eq = v[j] == T;
        if (!gt && !eq) continue;
        const int c = j * 4 + w;
        unsigned bq_gt = 0, bq_eq = 0;
        for (int cc = 0; cc < c; ++cc) { bq_gt += cgt[cc]; bq_eq += ceq[cc]; }
        const unsigned wgt = (unsigned)__popcll(bgt[j] & below);
        const unsigned weq = (unsigned)__popcll(beq[j] & below);
        unsigned pos;
        if (gt) {
            const unsigned eq_before = bq_eq + weq;
            pos = bq_gt + wgt + ((eq_before < kk) ? eq_before : kk);
        } else {
            const unsigned e = bq_eq + weq;     // global tie rank (index order)
            if (e >= kk) continue;
            pos = bq_gt + wgt + e;
        }
        selsort[b * TOK + pos] = (int)(t + 256 * j);
    }
}

// ---------------- kernel 6: gather + pos-embed ----------------
__global__ __launch_bounds__(256) void gather_kernel(const float* __restrict__ x,
                                                     const float* __restrict__ pos,
                                                     const int* __restrict__ selsort,
                                                     float* __restrict__ out) {
    const size_t i = (size_t)blockIdx.x * 256 + threadIdx.x;
    const size_t total = (size_t)BB * TOK * NJ * (CH / 4);
    if (i >= total) return;
    const int c4 = (int)(i & (CH / 4 - 1));
    size_t r = i >> 7;
    const int n = (int)(r % NJ); r /= NJ;
    const int t = (int)(r % TOK);
    const int b = (int)(r / TOK);
    const int f = selsort[b * TOK + t];
    float4 v = *(const float4*)(x + (((size_t)(b * FF + f)) * NJ + n) * CH + c4 * 4);
    const float4 p = *(const float4*)(pos + (size_t)t * CH + c4 * 4);
    v.x += p.x; v.y += p.y; v.z += p.z; v.w += p.w;
    *(float4*)(out + i * 4) = v;
}

extern "C" void kernel_launch(void* const* d_in, const int* in_sizes, int n_in,
                              void* d_out, int out_size, void* d_ws, size_t ws_size,
                              hipStream_t stream) {
    const float* x     = (const float*)d_in[0];
    const float* pos   = (const float*)d_in[1];
    const float* noise = (const float*)d_in[2];
    float* out = (float*)d_out;

    uint4* fhi    = (uint4*)d_ws;                           // 8 MB
    uint4* flo    = fhi + (size_t)BB * 32 * 2 * 1024;       // 8 MB
    float* dist   = (float*)(flo + (size_t)BB * 32 * 2 * 1024);  // 33.5 MB
    float* sq     = dist + (size_t)BB * FF * FF;
    float* density = sq + BB * FF;
    float* distmax = density + BB * FF;                     // 8 floats (atomicMax as uint)
    float* score   = distmax + 8;
    int*   selsort = (int*)(score + BB * FF);

    pool_kernel<<<(BB * FF) / 4, 256, 0, stream>>>(x, fhi, flo, sq, (unsigned*)distmax);
    dist_kernel<<<288, 256, 0, stream>>>(fhi, flo, sq, dist);   // flat grid, batch = id&7
    rowstat_kernel<<<(BB * FF) / 4, 256, 0, stream>>>(dist, noise, density, (unsigned*)distmax);
    scoremin_kernel<<<(BB * FF) / 4, 256, 0, stream>>>(dist, density, distmax, score);
    topk_kernel<<<BB, 256, 0, stream>>>(score, selsort);
    const int gtot = (int)(((size_t)BB * TOK * NJ * (CH / 4) + 255) / 256);
    gather_kernel<<<gtot, 256, 0, stream>>>(x, pos, selsort, out);
}